// Round 18
// baseline (89.228 us; speedup 1.0000x reference)
//
#include <hip/hip_runtime.h>
#include <utility>

// reference == inverse(M M^T + EPS*I) per pixel, M = x[b,:,:,h,w]^T (16x64)
// x: [B=4, C=64, K=16, H=128, W=128] f32 ; out: [B,H,W,16,16] f32
// Fused, 64 px/block, 1024 blocks, 256 threads (4 waves).
// KEY CHANGE vs r13: grid = 2x co-resident capacity (LDS 67.6KB -> 2 blocks/CU,
// 1024 blocks = 2 generations) so gen-2 gram READS overlap gen-1 tail WRITES.
//   phase 1: r6-proven gram: global_load_lds dbuf, 4-wave pair split acc[34]
//   phase 2: acc -> tri[136][67] (+EPS diag)
//   phase 3: r9-proven: wave 0, lane = pixel, REGISTER Cholesky->L^-1->M^T M
//   phase 4: r6-proven gather-store (thread = element, loop 64 px, coalesced)
// LDS: stage 2x16KB + tri 36.4KB = 67.6KB (NOT unioned, forces 2 blocks/CU);
// __launch_bounds__(256,2) -> 256-VGPR cap for phase-3's s[136].

#define EPSR 1e-6f

__device__ __host__ constexpr int rowof(int t) {
    int i = 0;
    while ((i + 1) * (i + 2) / 2 <= t) ++i;
    return i;
}
__device__ __host__ constexpr int colof(int t) { return t - rowof(t) * (rowof(t) + 1) / 2; }

__device__ __forceinline__ constexpr int tidx(int i, int j) {  // i >= j
    return i * (i + 1) / 2 + j;
}

#define GLOAD_LDS16(gp, lp)                                                       \
    __builtin_amdgcn_global_load_lds(                                             \
        (const __attribute__((address_space(1))) void*)(gp),                      \
        (__attribute__((address_space(3))) void*)(lp), 16, 0, 0)

// ---------------- pair-split template machinery (34/wave) ----------------

template<int P>
__device__ __forceinline__ void fma_pair(const float (&m)[16], float& a) {
    a = fmaf(m[rowof(P)], m[colof(P)], a);
}

template<int G, int... TT>
__device__ __forceinline__ void fma_group(const float (&m)[16], float (&acc)[34],
                                          std::integer_sequence<int, TT...>) {
    (fma_pair<G * 34 + TT>(m, acc[TT]), ...);
}

template<int G>
__device__ __forceinline__ void chunk_fma4(const float* __restrict__ buf, int lane,
                                           float (&acc)[34]) {
    #pragma unroll
    for (int cs = 0; cs < 4; ++cs) {
        float m[16];
        #pragma unroll
        for (int k = 0; k < 16; ++k) m[k] = buf[(cs * 16 + k) * 64 + lane];
        fma_group<G>(m, acc, std::make_integer_sequence<int, 34>{});
    }
}

template<int P>
__device__ __forceinline__ void store_tri_pair(float* __restrict__ tri, int lane, float v) {
    constexpr bool diag = (rowof(P) == colof(P));
    tri[P * 67 + lane] = diag ? (v + EPSR) : v;
}

template<int G, int... TT>
__device__ __forceinline__ void store_tri_group(float* __restrict__ tri, int lane,
                                                const float (&acc)[34],
                                                std::integer_sequence<int, TT...>) {
    (store_tri_pair<G * 34 + TT>(tri, lane, acc[TT]), ...);
}

// ---------------- fused kernel ----------------

__global__ __launch_bounds__(256, 2)
void fused_gram_inv(const float* __restrict__ x, float* __restrict__ out) {
    __shared__ __align__(16) float stage[2][4096];   // 2 x 16 KB: [c'*16+k][px 64]
    __shared__ float tri[136 * 67];                  // 36.4 KB

    const int tid = threadIdx.x;
    const int lane = tid & 63;
    const int wv = tid >> 6;                  // 0..3
    const int p0 = blockIdx.x * 64;
    const int b = blockIdx.x >> 8;            // 256 blocks per batch
    const int hw0 = p0 & 16383;

    // staging src: lane l covers k-row (l>>4) of a 4-row span, px (l&15)*4..+3
    const float* gbase = x + (size_t)b * 16777216 + hw0
                           + (size_t)(lane >> 4) * 16384 + (size_t)(lane & 15) * 4;

    float acc[34];
    #pragma unroll
    for (int t = 0; t < 34; ++t) acc[t] = 0.0f;

    // wave wv stages channel c0+wv: 4 instrs x (4 k-rows x 64 px) = 4 KB
    auto STAGE = [&](int bufi, int c0) {
        #pragma unroll
        for (int q = 0; q < 4; ++q) {
            GLOAD_LDS16(gbase + (size_t)(c0 + wv) * 262144 + (size_t)(q * 4) * 16384,
                        &stage[bufi][(wv * 16 + q * 4) * 64]);
        }
    };

    // ---- phase 1: gram, dbuf pipeline (16 chunks of 4 c) ----
    STAGE(0, 0);
    for (int t = 0; t < 16; ++t) {
        __syncthreads();                              // vmcnt(0) drain + barrier
        if (t < 15) STAGE((t + 1) & 1, 4 * (t + 1));  // prefetch next chunk
        const float* buf = stage[t & 1];
        switch (wv) {
            case 0:  chunk_fma4<0>(buf, lane, acc); break;
            case 1:  chunk_fma4<1>(buf, lane, acc); break;
            case 2:  chunk_fma4<2>(buf, lane, acc); break;
            default: chunk_fma4<3>(buf, lane, acc); break;
        }
    }

    // ---- phase 2: acc -> tri (+EPS on diag); disjoint rows per wave ----
    switch (wv) {
        case 0:  store_tri_group<0>(tri, lane, acc, std::make_integer_sequence<int, 34>{}); break;
        case 1:  store_tri_group<1>(tri, lane, acc, std::make_integer_sequence<int, 34>{}); break;
        case 2:  store_tri_group<2>(tri, lane, acc, std::make_integer_sequence<int, 34>{}); break;
        default: store_tri_group<3>(tri, lane, acc, std::make_integer_sequence<int, 34>{}); break;
    }
    __syncthreads();

    // ---- phase 3: wave 0, lane = pixel, REGISTER inversion (r9 body) ----
    if (wv == 0) {
        float s[136];
        #pragma unroll
        for (int t = 0; t < 136; ++t) s[t] = tri[t * 67 + lane];

        // Cholesky in place: off-diag = L[i][j], diag = 1/L[j][j]
        #pragma unroll
        for (int j = 0; j < 16; ++j) {
            float d = s[tidx(j, j)];
            #pragma unroll
            for (int q = 0; q < j; ++q) d = fmaf(-s[tidx(j, q)], s[tidx(j, q)], d);
            const float invd = 1.0f / sqrtf(d);
            s[tidx(j, j)] = invd;
            #pragma unroll
            for (int i = j + 1; i < 16; ++i) {
                float v = s[tidx(i, j)];
                #pragma unroll
                for (int q = 0; q < j; ++q) v = fmaf(-s[tidx(i, q)], s[tidx(j, q)], v);
                s[tidx(i, j)] = v * invd;
            }
        }

        // M = L^{-1} in place (diag already inverted)
        #pragma unroll
        for (int j = 0; j < 16; ++j) {
            #pragma unroll
            for (int i = j + 1; i < 16; ++i) {
                float sum = s[tidx(i, j)] * s[tidx(j, j)];
                #pragma unroll
                for (int q = j + 1; q < i; ++q)
                    sum = fmaf(s[tidx(i, q)], s[tidx(q, j)], sum);
                s[tidx(i, j)] = -s[tidx(i, i)] * sum;
            }
        }

        // A^{-1} = M^T M in place
        #pragma unroll
        for (int j = 0; j < 16; ++j) {
            #pragma unroll
            for (int i = j; i < 16; ++i) {
                float sum = 0.0f;
                #pragma unroll
                for (int q = i; q < 16; ++q)
                    sum = fmaf(s[tidx(q, i)], s[tidx(q, j)], sum);
                s[tidx(i, j)] = sum;
            }
        }

        // writeback
        #pragma unroll
        for (int t = 0; t < 136; ++t) tri[t * 67 + lane] = s[t];
    }
    __syncthreads();

    // ---- phase 4: gather-store, thread = output element e, loop 64 px ----
    const int e = tid;                  // 0..255 -> (i,j)
    const int i = e >> 4, j = e & 15;
    const int hi = i > j ? i : j;
    const int lo = i + j - hi;
    const int trow = hi * (hi + 1) / 2 + lo;
    float* gout = out + (size_t)p0 * 256;
    #pragma unroll 8
    for (int a = 0; a < 64; ++a) {
        gout[(size_t)a * 256 + e] = tri[trow * 67 + a];
    }
}

extern "C" void kernel_launch(void* const* d_in, const int* in_sizes, int n_in,
                              void* d_out, int out_size, void* d_ws, size_t ws_size,
                              hipStream_t stream) {
    const float* x = (const float*)d_in[0];
    float* out = (float*)d_out;
    hipLaunchKernelGGL(fused_gram_inv, dim3(1024), dim3(256), 0, stream, x, out);
}